// Round 10
// baseline (91.248 us; speedup 1.0000x reference)
//
#include <hip/hip_runtime.h>

// ---------------------------------------------------------------------------
// TaskAlignedAssigner (YOLO TAL) for MI355X — 2 dispatches, single IoU pass.
// B=32, A=8400, M=32, C=80 (derived at runtime; M<=32 so a gt-column mask
// fits one uint32 per anchor; C%4==0 assumed for float4 ts writes).
//
// Outputs (concatenated float32, return order):
//   tl (B,A) | tb (B,A,4) | ts (B,A,C) | fg (B,A) | tgt (B,A)
//
// R1: removed global atomic histogram (65us same-cacheline serialization).
// R2: fix2 wave-parallel register scan (was 71.7us dependent-latency).
// R3 (regressed): select1 inside 32-block fix2 -> 32/256 CUs busy.
// R4: select1 full-grid; 5 kernels + memset = 74.5us.
// R5 (regressed, 250us): cooperative kernel — grid.sync ~60-70us each.
// R6 (regressed, 127us): ticket+__threadfence — ~90us of L2 writeback.
// R7: 4 dispatches, no fences: 59.9us.
// R8: 2 dispatches (phase1 = columns+chunks merged grid; k_final recomputes
//     the serial tail per block + override list): 53.3us.
// R9: column tasks deleted — per-chunk column max computed IN the chunk task
//     from the same 32 IoU registers used for tgt0 (one IoU pass over pdb
//     instead of two; phase1 blocks 2080 -> 1056). k_final main pass skips
//     the select2 argmax: final tgt == tgt0 unless overridden (bits equal ->
//     same full-row argmax); override list carries final tgt, computed once
//     in the prologue. Main pass: short load + 1 IoU + gather + writes.
// ---------------------------------------------------------------------------

#define EPS_IN   1e-9f
#define IOU_EPS  1e-7f

// IoU exactly as reference (_iou_xyxy) with clip(.,0); fp contraction off so
// results are bit-identical across kernels and match plain IEEE numpy eval.
__device__ __forceinline__ float iou_pair(const float4 p, const float4 g) {
#pragma clang fp contract(off)
    float w1 = p.z - p.x;
    float h1 = (p.w - p.y) + IOU_EPS;
    float w2 = g.z - g.x;
    float h2 = (g.w - g.y) + IOU_EPS;
    float iw = fminf(p.z, g.z) - fmaxf(p.x, g.x);
    iw = fmaxf(iw, 0.0f);
    float ih = fminf(p.w, g.w) - fmaxf(p.y, g.y);
    ih = fmaxf(ih, 0.0f);
    float inter = iw * ih;
    float uni = w1 * h1 + w2 * h2 - inter + IOU_EPS;
    float r = inter / uni;
    return fmaxf(r, 0.0f);
}

// mask_gt dtype detection (int32 / f32 / u8), wave-uniform. mask[b][0] is
// always true (n_gt>=1) so each dtype is observable in the first nw words.
__device__ __forceinline__ int detect_mode(const void* mg, int nw) {
    const unsigned* w = (const unsigned*)mg;
    int lane = threadIdx.x & 63;
    int badI = 0, badF = 0;
    for (int i = lane; i < nw; i += 64) {
        unsigned v = w[i];
        badI |= (v > 1u);
        badF |= (v != 0u && v != 0x3F800000u);
    }
    unsigned long long bI = __ballot(badI != 0);
    unsigned long long bF = __ballot(badF != 0);
    return bI ? (bF ? 2 : 1) : 0;
}

__device__ __forceinline__ bool mask_at(const void* mg, int mode, int idx) {
    if (mode == 0) return ((const int*)mg)[idx] != 0;
    if (mode == 1) return ((const float*)mg)[idx] != 0.0f;
    return ((const unsigned char*)mg)[idx] != 0;
}

// K1: one pass over pdb. Per (b, chunk): 32 IoUs per anchor in registers ->
// (a) rowbits0 + tgt0 (select1, full-row argmax for pc>1) + LDS histogram
// -> cntChunk; (b) per-chunk column max keys -> colChunk (wave butterfly +
// ballot first-max tiebreak, merged across 4 waves); (c) hasin OR word.
__global__ void k_phase1(const float4* __restrict__ pdb, const float2* __restrict__ anc,
                         const float4* __restrict__ gtb, const void* mg, int nw,
                         unsigned long long* __restrict__ colChunk,
                         unsigned* __restrict__ hasinChunk,
                         unsigned* __restrict__ rowbits0, short* __restrict__ tgt0,
                         int* __restrict__ cntChunk,
                         int A, int M, int nCh) {
    int b = blockIdx.y, ch = blockIdx.x, tid = threadIdx.x;
    int lane = tid & 63, wid = tid >> 6;
    int mode = detect_mode(mg, nw);
    __shared__ float4 sg[32];
    __shared__ unsigned sMask;
    __shared__ float swv[4][32];
    __shared__ int   swa[4][32];
    __shared__ unsigned swh[4];
    __shared__ int shist[32];
    if (tid < 32) {
        sg[tid] = (tid < M) ? gtb[b * M + tid] : make_float4(0.f, 0.f, 0.f, 0.f);
        shist[tid] = 0;
    }
    if (tid < 64) {
        bool mv = (tid < M) && mask_at(mg, mode, b * M + tid);
        unsigned mb = (unsigned)__ballot(mv);
        if (tid == 0) sMask = mb;
    }
    __syncthreads();
    unsigned maskb = sMask;
    size_t bA = (size_t)b * A;
    int a = ch * 256 + tid;
    bool valid = a < A;
    float4 p = make_float4(0.f, 0.f, 0.f, 0.f);
    float2 an = make_float2(0.f, 0.f);
    if (valid) { p = pdb[bA + a]; an = anc[a]; }
    float v[32];
    unsigned inbox = 0u;
#pragma unroll
    for (int m = 0; m < 32; m++) {
        float4 g = sg[m];
        bool ok = valid && (m < M);
        v[m] = ok ? iou_pair(p, g) : -1.0f;
        float mn = fminf(fminf(an.x - g.x, an.y - g.y), fminf(g.z - an.x, g.w - an.y));
        if (ok && mn > EPS_IN) inbox |= (1u << m);
    }
    if (valid) {
        unsigned bits = inbox & maskb;
        int pc = __popc(bits);
        int t = -1;
        if (pc > 1) {
            float bv = -0.5f; int bm = 0;
#pragma unroll
            for (int m = 0; m < 32; m++) { if (v[m] > bv) { bv = v[m]; bm = m; } }
            t = bm;                                   // full-row first-max
        } else if (pc == 1) t = __ffs(bits) - 1;
        rowbits0[bA + a] = bits;
        tgt0[bA + a] = (short)t;
        if (t >= 0) atomicAdd(&shist[t], 1);
    } else if (a < ((A + 255) & ~255)) {
        // keep rowbits0/tgt0 deterministic only where read: never read for a>=A
    }
    // hasin OR (geometry, pre-mask) per wave
    unsigned hw = inbox;
    for (int off = 32; off; off >>= 1) hw |= __shfl_xor(hw, off);
    if (lane == 0) swh[wid] = hw;
    // per-wave column max per m: butterfly max + ballot first-index tiebreak
#pragma unroll
    for (int m = 0; m < 32; m++) {
        float vm = v[m];
        for (int off = 32; off; off >>= 1) vm = fmaxf(vm, __shfl_xor(vm, off));
        unsigned long long eq = __ballot(v[m] == vm);
        if (lane == 0) {
            swv[wid][m] = vm;
            swa[wid][m] = ch * 256 + wid * 64 + (__ffsll((unsigned long long)eq) - 1);
        }
    }
    __syncthreads();
    if (tid < 32) {
        float bv = swv[0][tid]; int ba = swa[0][tid];
        for (int w = 1; w < 4; w++) {
            float vv = swv[w][tid]; int aa = swa[w][tid];
            if (vv > bv || (vv == bv && aa < ba)) { bv = vv; ba = aa; }
        }
        unsigned long long key = (bv < 0.0f) ? 0ull :
            (((unsigned long long)__float_as_uint(bv) << 32) | (0xFFFFFFFFu - (unsigned)ba));
        colChunk[((size_t)b * nCh + ch) * 32 + tid] = key;
        cntChunk[((size_t)b * nCh + ch) * 32 + tid] = shist[tid];
        if (tid == 0) hasinChunk[b * nCh + ch] = swh[0] | swh[1] | swh[2] | swh[3];
    }
}

// K2: prologue (wave 0): reduce colChunk/hasin/cnt over chunks; fix1 groups
// (adjust counts + pre-owners, record adds); fix2 32-step register scan
// (record adds); finalize override list -> final tgt per overridden anchor.
// Main pass: t = tgt0 (short load) unless overridden; 1 IoU; gather; writes;
// block-cooperative float4 ts write.
__global__ void k_final(const float* __restrict__ pds, const float4* __restrict__ pdb,
                        const float4* __restrict__ gtb, const int* __restrict__ gtl,
                        const void* mg, int nw,
                        const unsigned long long* __restrict__ colChunk,
                        const unsigned* __restrict__ hasinChunk,
                        const unsigned* __restrict__ rowbits0,
                        const short* __restrict__ tgt0,
                        const int* __restrict__ cntChunk,
                        float* __restrict__ out,
                        int A, int M, int C, int B, int nCh) {
    int b = blockIdx.y;
    int base = blockIdx.x * 256;
    int tid = threadIdx.x;
    int mode = detect_mode(mg, nw);
    size_t bA = (size_t)b * A;
    __shared__ float4 sg[32];
    __shared__ int slab[32];
    __shared__ int ovrA[64];
    __shared__ unsigned ovrAdd[64];
    __shared__ short ovrT[64];
    __shared__ int sNov;
    __shared__ float snorm[256];
    __shared__ int stl[256];
    if (tid < 32) {
        sg[tid]   = (tid < M) ? gtb[b * M + tid] : make_float4(0.f, 0.f, 0.f, 0.f);
        slab[tid] = (tid < M) ? gtl[b * M + tid] : 0;
    }
    __syncthreads();

    if (tid < 64) {
        bool mv = (tid < M) && mask_at(mg, mode, b * M + tid);
        unsigned long long key = 0ull;
        int c0 = 0; unsigned horAll = 0u;
        if (tid < 32) {
            for (int ch = 0; ch < nCh; ch++) {
                unsigned long long k2 = colChunk[((size_t)b * nCh + ch) * 32 + tid];
                if (k2 > key) key = k2;
                c0 += cntChunk[((size_t)b * nCh + ch) * 32 + tid];
                horAll |= hasinChunk[b * nCh + ch];
            }
        }
        int best = mv ? (int)(0xFFFFFFFFu - (unsigned)(key & 0xFFFFFFFFull)) : -1;
        bool needv = mv && !((horAll >> tid) & 1u);
        int myPre = (best >= 0) ? (int)tgt0[bA + best] : -1;
        unsigned maskbits = (unsigned)__ballot(mv);
        unsigned needBits = (unsigned)__ballot(needv);
        unsigned myEq = 0u;
        for (int g2 = 0; g2 < 32; g2++) {
            int bb = __shfl(best, g2);
            if (bb == best) myEq |= (1u << g2);
        }
        int nov = 0;
        // ---- fix1: groups of needy gts sharing the same best anchor ----
        unsigned rem = needBits;
        while (rem) {
            int gl = __ffs(rem) - 1;
            unsigned em = __shfl(myEq, gl) & needBits;
            rem &= ~em;
            int aF = __shfl(best, gl);
            unsigned addb = em;
            unsigned bits1 = rowbits0[bA + aF] | addb;
            int t1;
            if (__popc(bits1) > 1) {
                float4 p = pdb[bA + aF];
                unsigned long long kk = 0ull;
                if (tid < M) {
                    float vv = iou_pair(p, sg[tid]);
                    kk = ((unsigned long long)__float_as_uint(vv) << 32) |
                         (0xFFFFFFFFu - (unsigned)tid);
                }
                for (int off = 32; off; off >>= 1) {
                    unsigned long long o = __shfl_down(kk, off);
                    if (o > kk) kk = o;
                }
                kk = __shfl(kk, 0);
                t1 = (int)(0xFFFFFFFFu - (unsigned)(kk & 0xFFFFFFFFull));
            } else {
                t1 = __ffs(bits1) - 1;
            }
            int t0a = __shfl(myPre, gl);
            if (tid == t0a && t0a >= 0) c0--;
            if (tid == t1) c0++;
            if (best == aF) myPre = t1;
            if (tid == 0) { ovrA[nov] = aF; ovrAdd[nov] = addb; }
            nov++;
        }
        // ---- fix2: order-dependent 32-step scan in registers ----
        unsigned applied = 0u;
        for (int g = 0; g < M; g++) {
            int cg = __shfl(c0, g);
            if (((maskbits >> g) & 1u) && cg == 0) {
                int aa      = __shfl(best, g);
                unsigned em = __shfl(myEq, g);
                unsigned x  = applied & em;
                int old;
                if (x) old = 31 - __clz(x);
                else   old = __shfl(myPre, g);
                if (tid == old) c0--;
                if (tid == g)   c0++;
                applied |= (1u << g);
                if (tid == 0) { ovrA[nov] = aa; ovrAdd[nov] = 1u << g; }
                nov++;
            }
        }
        if (tid == 0) sNov = nov;
    }
    __syncthreads();
    // ---- finalize overrides: compute final tgt per entry (wave 0) ----
    if (tid < 64) {
        int nov2 = sNov;
        for (int j = 0; j < nov2; j++) {
            int aj = ovrA[j];
            unsigned addT = 0u;
            for (int k = 0; k < nov2; k++) if (ovrA[k] == aj) addT |= ovrAdd[k];
            unsigned bt = rowbits0[bA + aj] | addT;
            int tf;
            if (__popc(bt) > 1) {
                float4 p = pdb[bA + aj];
                unsigned long long kk = 0ull;
                if (tid < M) {
                    float vv = iou_pair(p, sg[tid]);
                    kk = ((unsigned long long)__float_as_uint(vv) << 32) |
                         (0xFFFFFFFFu - (unsigned)tid);
                }
                for (int off = 32; off; off >>= 1) {
                    unsigned long long o = __shfl_down(kk, off);
                    if (o > kk) kk = o;
                }
                kk = __shfl(kk, 0);
                tf = (int)(0xFFFFFFFFu - (unsigned)(kk & 0xFFFFFFFFull));
            } else {
                tf = __ffs(bt) - 1;
            }
            if (tid == 0) ovrT[j] = (short)tf;
        }
    }
    __syncthreads();

    // ---- main: per-anchor outputs (no argmax; tgt0 + override list) ----
    int a = base + tid;
    size_t BA = (size_t)B * A;
    if (a < A) {
        size_t idx = bA + a;
        int t = (int)tgt0[idx];
        int nov2 = sNov;
        for (int j = 0; j < nov2; j++)
            if (ovrA[j] == a) t = (int)ovrT[j];
        int fg = (t >= 0);
        int tgtO = fg ? t : 0;
        int lab = slab[tgtO];
        int tl = min(max(lab, 0), C);            // clip(., 0, NUM_CLASSES)
        float norm = 0.0f;
        if (fg) {
            float ov = iou_pair(pdb[idx], sg[t]);
            int li = (lab >= 0 && lab < C) ? lab : 0;
            float cls = pds[idx * (size_t)C + li];
            float ov6 = powf(ov, 6.0f);          // overlaps ** BETA
            float vv = cls * ov6;                // align_metric at (a, tgt)
            norm = vv * ov / (vv + 1e-9f);       // pam*pov/(pam+eps)
        }
        out[idx] = (float)tl;                                // tl
        ((float4*)(out + BA))[idx] = sg[tgtO];               // tb
        out[BA * (size_t)(5 + C) + idx] = fg ? 1.0f : 0.0f;  // fg
        out[BA * (size_t)(6 + C) + idx] = (float)tgtO;       // tgt
        snorm[tid] = norm;
        stl[tid] = tl;
    }
    __syncthreads();
    int cntA = min(256, A - base);
    int rowf4 = C >> 2;
    int nf4 = cntA * rowf4;
    float4* tsb = (float4*)(out + BA * 5 + (bA + base) * C);
    int q = 256 / rowf4, r = 256 - q * rowf4;
    int row = tid / rowf4;
    int c4  = tid - row * rowf4;
    for (int i = tid; i < nf4; i += 256) {
        float nv = snorm[row];
        int tl   = stl[row];
        int cb = c4 * 4;
        float4 vv;
        vv.x = (tl == cb + 0) ? nv : 0.0f;
        vv.y = (tl == cb + 1) ? nv : 0.0f;
        vv.z = (tl == cb + 2) ? nv : 0.0f;
        vv.w = (tl == cb + 3) ? nv : 0.0f;
        tsb[i] = vv;
        row += q; c4 += r;
        if (c4 >= rowf4) { c4 -= rowf4; row++; }
    }
}

extern "C" void kernel_launch(void* const* d_in, const int* in_sizes, int n_in,
                              void* d_out, int out_size, void* d_ws, size_t ws_size,
                              hipStream_t stream) {
    const float*  pd_scores = (const float*)d_in[0];
    const float4* pd_bboxes = (const float4*)d_in[1];
    const float2* anc       = (const float2*)d_in[2];
    const int*    gt_labels = (const int*)d_in[3];
    const float4* gt_bboxes = (const float4*)d_in[4];
    const void*   mask_gt   = d_in[5];

    int A = in_sizes[2] / 2;
    int B = in_sizes[1] / (A * 4);
    int M = in_sizes[3] / B;
    int C = (int)((long long)in_sizes[0] / ((long long)B * A));
    int nCh = (A + 255) / 256;
    int nw = (B * M) / 4; if (nw > 256) nw = 256;

    char* wp = (char*)d_ws;
    auto carve = [&](size_t bytes) -> char* {
        char* r = wp; wp += (bytes + 255) & ~(size_t)255; return r;
    };
    unsigned* rowbits0         = (unsigned*)carve((size_t)B * A * 4);
    short* tgt0                = (short*)carve((size_t)B * A * 2);
    unsigned long long* colChunk = (unsigned long long*)carve((size_t)B * nCh * 32 * 8);
    unsigned* hasinChunk       = (unsigned*)carve((size_t)B * nCh * 4);
    int* cntChunk              = (int*)carve((size_t)B * nCh * 32 * 4);

    float* out = (float*)d_out;

    k_phase1<<<dim3(nCh, B), 256, 0, stream>>>(pd_bboxes, anc, gt_bboxes, mask_gt, nw,
                                               colChunk, hasinChunk, rowbits0, tgt0,
                                               cntChunk, A, M, nCh);
    k_final<<<dim3(nCh, B), 256, 0, stream>>>(pd_scores, pd_bboxes, gt_bboxes, gt_labels,
                                              mask_gt, nw, colChunk, hasinChunk,
                                              rowbits0, tgt0, cntChunk, out,
                                              A, M, C, B, nCh);
}

// Round 11
// 51.665 us; speedup vs baseline: 1.7661x; 1.7661x over previous
//
#include <hip/hip_runtime.h>

// ---------------------------------------------------------------------------
// TaskAlignedAssigner (YOLO TAL) for MI355X — 2 dispatches.
// B=32, A=8400, M=32, C=80 (derived at runtime; M<=32 so a gt-column mask
// fits one uint32 per anchor; C%4==0 assumed for float4 ts writes).
//
// Outputs (concatenated float32, return order):
//   tl (B,A) | tb (B,A,4) | ts (B,A,C) | fg (B,A) | tgt (B,A)
//
// R1: removed global atomic histogram (65us same-cacheline serialization).
// R2: fix2 wave-parallel register scan (was 71.7us dependent-latency).
// R3 (regressed): select1 inside 32-block fix2 -> 32/256 CUs busy.
// R4: select1 full-grid; 5 kernels + memset = 74.5us.
// R5 (regressed, 250us): cooperative kernel — grid.sync ~60-70us each.
// R6 (regressed, 127us): ticket+__threadfence — ~90us of L2 writeback.
// R7: 4 dispatches, no fences: 59.9us.
// R8: 2 dispatches (phase1 = columns+chunks merged; k_final serial-tail
//     recompute + override list): 53.3us.
// R9 (regressed, 91us): fused column reduce into chunk task -> v[32] spilled
//     to scratch (FETCH 31.6MB = 128B/thread round-trip; VGPR 64) + 1056x
//     more cross-lane ops. Recompute is cheaper than per-chunk reduction.
// R10: R8's k_phase1 (proven) + R9's light k_final main pass (tgt = tgt0
//     unless overridden; override list carries final tgt computed in the
//     prologue). Main pass: short load + 1 IoU + gather + writes.
// ---------------------------------------------------------------------------

#define EPS_IN   1e-9f
#define IOU_EPS  1e-7f

// IoU exactly as reference (_iou_xyxy) with clip(.,0); fp contraction off so
// results are bit-identical across kernels and match plain IEEE numpy eval.
__device__ __forceinline__ float iou_pair(const float4 p, const float4 g) {
#pragma clang fp contract(off)
    float w1 = p.z - p.x;
    float h1 = (p.w - p.y) + IOU_EPS;
    float w2 = g.z - g.x;
    float h2 = (g.w - g.y) + IOU_EPS;
    float iw = fminf(p.z, g.z) - fmaxf(p.x, g.x);
    iw = fmaxf(iw, 0.0f);
    float ih = fminf(p.w, g.w) - fmaxf(p.y, g.y);
    ih = fmaxf(ih, 0.0f);
    float inter = iw * ih;
    float uni = w1 * h1 + w2 * h2 - inter + IOU_EPS;
    float r = inter / uni;
    return fmaxf(r, 0.0f);
}

// mask_gt dtype detection (int32 / f32 / u8), wave-uniform. mask[b][0] is
// always true (n_gt>=1) so each dtype is observable in the first nw words.
__device__ __forceinline__ int detect_mode(const void* mg, int nw) {
    const unsigned* w = (const unsigned*)mg;
    int lane = threadIdx.x & 63;
    int badI = 0, badF = 0;
    for (int i = lane; i < nw; i += 64) {
        unsigned v = w[i];
        badI |= (v > 1u);
        badF |= (v != 0u && v != 0x3F800000u);
    }
    unsigned long long bI = __ballot(badI != 0);
    unsigned long long bF = __ballot(badF != 0);
    return bI ? (bF ? 2 : 1) : 0;
}

__device__ __forceinline__ bool mask_at(const void* mg, int mode, int idx) {
    if (mode == 0) return ((const int*)mg)[idx] != 0;
    if (mode == 1) return ((const float*)mg)[idx] != 0.0f;
    return ((const unsigned char*)mg)[idx] != 0;
}

// K1: merged column+anchor pass (independent halves, disjoint outputs).
//  blockIdx.x <  M  : column task (b,m): masked -> colKey (argmax_a overlaps,
//                     first-index tiebreak) + hasin -> needByte.
//  blockIdx.x >= M  : chunk task (b,ch): in-box bits -> rowbits0 (plain),
//                     select1 (no fix1) -> tgt0, per-chunk histogram ->
//                     cntChunk[b][ch][32] (plain stores, no atomics).
__global__ void k_phase1(const float4* __restrict__ pdb, const float2* __restrict__ anc,
                         const float4* __restrict__ gtb, const void* mg, int nw,
                         unsigned long long* __restrict__ colKey,
                         unsigned char* __restrict__ needByte,
                         unsigned* __restrict__ rowbits0, short* __restrict__ tgt0,
                         int* __restrict__ cntChunk,
                         int A, int M, int nCh) {
    int b = blockIdx.y, tid = threadIdx.x;
    int mode = detect_mode(mg, nw);
    size_t bA = (size_t)b * A;

    if ((int)blockIdx.x < M) {
        // ---- column task ----
        int m = blockIdx.x;
        if (!mask_at(mg, mode, b * M + m)) return;
        float4 g = gtb[b * M + m];
        unsigned long long key = 0ull;
        int hasin = 0;
        for (int a = tid; a < A; a += 256) {
            float v = iou_pair(pdb[bA + a], g);
            unsigned long long k =
                ((unsigned long long)__float_as_uint(v) << 32) | (0xFFFFFFFFu - (unsigned)a);
            if (k > key) key = k;
            float2 an = anc[a];
            float mn = fminf(fminf(an.x - g.x, an.y - g.y), fminf(g.z - an.x, g.w - an.y));
            hasin |= (mn > EPS_IN);
        }
        __shared__ unsigned long long skey[4];
        __shared__ int sin_[4];
        int lane = tid & 63, wid = tid >> 6;
        for (int off = 32; off; off >>= 1) {
            unsigned long long o = __shfl_down(key, off);
            if (o > key) key = o;
            hasin |= __shfl_down(hasin, off);
        }
        if (lane == 0) { skey[wid] = key; sin_[wid] = hasin; }
        __syncthreads();
        if (tid == 0) {
            for (int i = 1; i < 4; i++) { if (skey[i] > key) key = skey[i]; hasin |= sin_[i]; }
            colKey[b * M + m] = key;
            needByte[b * M + m] = hasin ? 0 : 1;
        }
    } else {
        // ---- chunk task ----
        int ch = blockIdx.x - M;
        int a = ch * 256 + tid;
        __shared__ float4 sg[32];
        __shared__ unsigned char smg[32];
        __shared__ int shist[32];
        if (tid < M) {
            sg[tid]  = gtb[b * M + tid];
            smg[tid] = mask_at(mg, mode, b * M + tid) ? 1 : 0;
        }
        if (tid < 32) shist[tid] = 0;
        __syncthreads();
        if (a < A) {
            float2 an = anc[a];
            unsigned bits = 0u;
            for (int m = 0; m < M; m++) {
                float4 g = sg[m];
                float mn = fminf(fminf(an.x - g.x, an.y - g.y), fminf(g.z - an.x, g.w - an.y));
                if (mn > EPS_IN && smg[m]) bits |= (1u << m);
            }
            rowbits0[bA + a] = bits;
            int pc = __popc(bits);
            int t;
            if (pc > 1) {
                float4 p = pdb[bA + a];
                float bv = -1.0f; int bm = 0;
                for (int m = 0; m < M; m++) {
                    float v = iou_pair(p, sg[m]);
                    if (v > bv) { bv = v; bm = m; }
                }
                t = bm;
            } else if (pc == 1) t = __ffs(bits) - 1;
            else t = -1;
            tgt0[bA + a] = (short)t;
            if (t >= 0) atomicAdd(&shist[t], 1);
        }
        __syncthreads();
        if (tid < 32) cntChunk[((size_t)b * nCh + ch) * 32 + tid] = shist[tid];
    }
}

// K2: prologue (wave 0): cnt0 = sum cntChunk; fix1 groups (adjust counts +
// pre-owners, record adds); fix2 32-step register scan (record adds);
// finalize override list -> final tgt per overridden anchor (32-lane IoU
// argmax on merged bits). Main pass: t = tgt0 (short load) unless
// overridden; 1 IoU; gather; writes; block-cooperative float4 ts write.
__global__ void k_final(const float* __restrict__ pds, const float4* __restrict__ pdb,
                        const float4* __restrict__ gtb, const int* __restrict__ gtl,
                        const void* mg, int nw,
                        const unsigned long long* __restrict__ colKey,
                        const unsigned char* __restrict__ needByte,
                        const unsigned* __restrict__ rowbits0,
                        const short* __restrict__ tgt0,
                        const int* __restrict__ cntChunk,
                        float* __restrict__ out,
                        int A, int M, int C, int B, int nCh) {
    int b = blockIdx.y;
    int base = blockIdx.x * 256;
    int tid = threadIdx.x;
    int mode = detect_mode(mg, nw);
    size_t bA = (size_t)b * A;
    __shared__ float4 sg[32];
    __shared__ int slab[32];
    __shared__ int ovrA[64];
    __shared__ unsigned ovrAdd[64];
    __shared__ short ovrT[64];
    __shared__ int sNov;
    __shared__ float snorm[256];
    __shared__ int stl[256];
    if (tid < 32) {
        sg[tid]   = (tid < M) ? gtb[b * M + tid] : make_float4(0.f, 0.f, 0.f, 0.f);
        slab[tid] = (tid < M) ? gtl[b * M + tid] : 0;
    }
    __syncthreads();

    if (tid < 64) {
        // ---- lane state (lane g<32 owns gt g) ----
        bool mv = false, needv = false;
        int best = -1, c0 = 0;
        if (tid < M) mv = mask_at(mg, mode, b * M + tid);
        if (mv) {
            unsigned long long key = colKey[b * M + tid];
            best = (int)(0xFFFFFFFFu - (unsigned)(key & 0xFFFFFFFFull));
            needv = (needByte[b * M + tid] != 0);
        }
        if (tid < 32) {
            for (int ch = 0; ch < nCh; ch++)
                c0 += cntChunk[((size_t)b * nCh + ch) * 32 + tid];
        }
        int myPre = (mv && best >= 0) ? (int)tgt0[bA + best] : -1;
        unsigned maskbits = (unsigned)__ballot(mv);
        unsigned needBits = (unsigned)__ballot(needv);
        unsigned myEq = 0u;
        for (int g2 = 0; g2 < 32; g2++) {
            int bb = __shfl(best, g2);
            if (bb == best) myEq |= (1u << g2);
        }
        int nov = 0;
        // ---- fix1: groups of needy gts sharing the same best anchor ----
        unsigned rem = needBits;
        while (rem) {
            int gl = __ffs(rem) - 1;                       // group leader
            unsigned em = __shfl(myEq, gl) & needBits;     // group members
            rem &= ~em;
            int aF = __shfl(best, gl);
            unsigned addb = em;                            // bits added to aF
            unsigned bits1 = rowbits0[bA + aF] | addb;
            int t1;
            if (__popc(bits1) > 1) {
                // select1 recompute: full-row IoU argmax (first-max tiebreak)
                float4 p = pdb[bA + aF];
                unsigned long long kk = 0ull;
                if (tid < M) {
                    float vv = iou_pair(p, sg[tid]);
                    kk = ((unsigned long long)__float_as_uint(vv) << 32) |
                         (0xFFFFFFFFu - (unsigned)tid);
                }
                for (int off = 32; off; off >>= 1) {
                    unsigned long long o = __shfl_down(kk, off);
                    if (o > kk) kk = o;
                }
                kk = __shfl(kk, 0);
                t1 = (int)(0xFFFFFFFFu - (unsigned)(kk & 0xFFFFFFFFull));
            } else {
                t1 = __ffs(bits1) - 1;                     // bits0 was empty
            }
            int t0a = __shfl(myPre, gl);                   // tgt0[aF]
            if (tid == t0a && t0a >= 0) c0--;              // count adjust
            if (tid == t1) c0++;
            if (best == aF) myPre = t1;                    // new pre-owner
            if (tid == 0) { ovrA[nov] = aF; ovrAdd[nov] = addb; }
            nov++;
        }
        // ---- fix2: order-dependent 32-step scan in registers ----
        unsigned applied = 0u;
        for (int g = 0; g < M; g++) {
            int cg = __shfl(c0, g);
            if (((maskbits >> g) & 1u) && cg == 0) {
                int aa      = __shfl(best, g);
                unsigned em = __shfl(myEq, g);
                unsigned x  = applied & em;
                int old;
                if (x) old = 31 - __clz(x);    // last earlier step took this anchor
                else   old = __shfl(myPre, g); // owner after fix1 (-1 = background)
                if (tid == old) c0--;
                if (tid == g)   c0++;
                applied |= (1u << g);
                if (tid == 0) { ovrA[nov] = aa; ovrAdd[nov] = 1u << g; }
                nov++;
            }
        }
        if (tid == 0) sNov = nov;
    }
    __syncthreads();
    // ---- finalize overrides: final tgt per entry (wave 0) ----
    if (tid < 64) {
        int nov2 = sNov;
        for (int j = 0; j < nov2; j++) {
            int aj = ovrA[j];
            unsigned addT = 0u;
            for (int k = 0; k < nov2; k++) if (ovrA[k] == aj) addT |= ovrAdd[k];
            unsigned bt = rowbits0[bA + aj] | addT;
            int tf;
            if (__popc(bt) > 1) {
                float4 p = pdb[bA + aj];
                unsigned long long kk = 0ull;
                if (tid < M) {
                    float vv = iou_pair(p, sg[tid]);
                    kk = ((unsigned long long)__float_as_uint(vv) << 32) |
                         (0xFFFFFFFFu - (unsigned)tid);
                }
                for (int off = 32; off; off >>= 1) {
                    unsigned long long o = __shfl_down(kk, off);
                    if (o > kk) kk = o;
                }
                kk = __shfl(kk, 0);
                tf = (int)(0xFFFFFFFFu - (unsigned)(kk & 0xFFFFFFFFull));
            } else {
                tf = __ffs(bt) - 1;
            }
            if (tid == 0) ovrT[j] = (short)tf;
        }
    }
    __syncthreads();

    // ---- main: per-anchor outputs (no argmax; tgt0 + override list) ----
    int a = base + tid;
    size_t BA = (size_t)B * A;
    if (a < A) {
        size_t idx = bA + a;
        int t = (int)tgt0[idx];
        int nov2 = sNov;
        for (int j = 0; j < nov2; j++)
            if (ovrA[j] == a) t = (int)ovrT[j];
        int fg = (t >= 0);
        int tgtO = fg ? t : 0;
        int lab = slab[tgtO];
        int tl = min(max(lab, 0), C);            // clip(., 0, NUM_CLASSES)
        float norm = 0.0f;
        if (fg) {
            float ov = iou_pair(pdb[idx], sg[t]);
            int li = (lab >= 0 && lab < C) ? lab : 0;
            float cls = pds[idx * (size_t)C + li];
            float ov6 = powf(ov, 6.0f);          // overlaps ** BETA
            float vv = cls * ov6;                // align_metric at (a, tgt)
            norm = vv * ov / (vv + 1e-9f);       // pam*pov/(pam+eps)
        }
        out[idx] = (float)tl;                                // tl
        ((float4*)(out + BA))[idx] = sg[tgtO];               // tb
        out[BA * (size_t)(5 + C) + idx] = fg ? 1.0f : 0.0f;  // fg
        out[BA * (size_t)(6 + C) + idx] = (float)tgtO;       // tgt
        snorm[tid] = norm;
        stl[tid] = tl;
    }
    __syncthreads();
    int cntA = min(256, A - base);
    int rowf4 = C >> 2;
    int nf4 = cntA * rowf4;
    float4* tsb = (float4*)(out + BA * 5 + (bA + base) * C);
    int q = 256 / rowf4, r = 256 - q * rowf4;
    int row = tid / rowf4;
    int c4  = tid - row * rowf4;
    for (int i = tid; i < nf4; i += 256) {
        float nv = snorm[row];
        int tl   = stl[row];
        int cb = c4 * 4;
        float4 vv;
        vv.x = (tl == cb + 0) ? nv : 0.0f;
        vv.y = (tl == cb + 1) ? nv : 0.0f;
        vv.z = (tl == cb + 2) ? nv : 0.0f;
        vv.w = (tl == cb + 3) ? nv : 0.0f;
        tsb[i] = vv;
        row += q; c4 += r;
        if (c4 >= rowf4) { c4 -= rowf4; row++; }
    }
}

extern "C" void kernel_launch(void* const* d_in, const int* in_sizes, int n_in,
                              void* d_out, int out_size, void* d_ws, size_t ws_size,
                              hipStream_t stream) {
    const float*  pd_scores = (const float*)d_in[0];
    const float4* pd_bboxes = (const float4*)d_in[1];
    const float2* anc       = (const float2*)d_in[2];
    const int*    gt_labels = (const int*)d_in[3];
    const float4* gt_bboxes = (const float4*)d_in[4];
    const void*   mask_gt   = d_in[5];

    int A = in_sizes[2] / 2;
    int B = in_sizes[1] / (A * 4);
    int M = in_sizes[3] / B;
    int C = (int)((long long)in_sizes[0] / ((long long)B * A));
    int nCh = (A + 255) / 256;
    int nw = (B * M) / 4; if (nw > 256) nw = 256;

    char* wp = (char*)d_ws;
    auto carve = [&](size_t bytes) -> char* {
        char* r = wp; wp += (bytes + 255) & ~(size_t)255; return r;
    };
    unsigned* rowbits0         = (unsigned*)carve((size_t)B * A * 4);
    short* tgt0                = (short*)carve((size_t)B * A * 2);
    unsigned long long* colKey = (unsigned long long*)carve((size_t)B * M * 8);
    unsigned char* needByte    = (unsigned char*)carve((size_t)B * M);
    int* cntChunk              = (int*)carve((size_t)B * nCh * 32 * 4);

    float* out = (float*)d_out;

    k_phase1<<<dim3(M + nCh, B), 256, 0, stream>>>(pd_bboxes, anc, gt_bboxes, mask_gt, nw,
                                                   colKey, needByte, rowbits0, tgt0,
                                                   cntChunk, A, M, nCh);
    k_final<<<dim3(nCh, B), 256, 0, stream>>>(pd_scores, pd_bboxes, gt_bboxes, gt_labels,
                                              mask_gt, nw, colKey, needByte, rowbits0,
                                              tgt0, cntChunk, out, A, M, C, B, nCh);
}